// Round 4
// baseline (1607.751 us; speedup 1.0000x reference)
//
#include <hip/hip_runtime.h>
#include <hip/hip_bf16.h>

#define N_NODES 100000
#define FIN 128
#define HID 16
#define NCLS 40
#define NEDGE 3200000
#define NBUCK 782   // ceil(N_NODES / 128): 128 dst-nodes per bucket
#define XS_LD 132   // padded row stride (floats) for x tile: 528B = 33*16, aligned
#define W_LD 132    // padded row stride for transposed weight panel

typedef __hip_bfloat16 bf16;

// ---------------------------------------------------------------------------
// proj1: xw1b = bf16(x @ W1[1]), xr1 = x @ root1 (fp32).
// Block: 256 threads, 64 nodes. Thread micro-tile: 4 nodes x 2 cols.
// tx = tid&15 -> cols 2tx,2tx+1 (cols 0..15 = W1[1], 16..31 = root1).
// ty = tid>>4 -> nodes ty*4..ty*4+3. All LDS reads are ds_read_b128.
// ---------------------------------------------------------------------------
__global__ __launch_bounds__(256) void proj1_kernel(
    const float* __restrict__ x, const float* __restrict__ W1,
    const float* __restrict__ root1,
    bf16* __restrict__ xw1b, float* __restrict__ xr1) {
  __shared__ float xs[64 * XS_LD];   // 33 KB
  __shared__ float WLt[32 * W_LD];   // 16.5 KB, [col][i] transposed

  int tid = threadIdx.x;
  int node0 = blockIdx.x * 64;

  // stage transposed weights (one-time scalar loads)
  for (int t = tid; t < 32 * FIN; t += 256) {
    int c = t >> 7, i = t & 127;
    WLt[c * W_LD + i] =
        (c < 16) ? W1[FIN * HID + i * HID + c] : root1[i * HID + (c - 16)];
  }
  // stage 64 x-rows (float4, guarded tail)
#pragma unroll
  for (int k = 0; k < 8; ++k) {
    int f = k * 256 + tid;   // 0..2047 float4 slots
    int r = f >> 5;
    int cw = f & 31;
    float4 v = make_float4(0.f, 0.f, 0.f, 0.f);
    if (node0 + r < N_NODES)
      v = *(const float4*)(x + (size_t)(node0 + r) * FIN + cw * 4);
    *(float4*)(xs + r * XS_LD + cw * 4) = v;
  }
  __syncthreads();

  int tx = tid & 15;
  int ty = tid >> 4;
  const float* w0 = WLt + (2 * tx) * W_LD;
  const float* w1 = w0 + W_LD;
  const float* xrow = xs + (ty * 4) * XS_LD;

  float acc[4][2] = {{0.f, 0.f}, {0.f, 0.f}, {0.f, 0.f}, {0.f, 0.f}};
#pragma unroll 8
  for (int i = 0; i < FIN; i += 4) {
    float4 b0 = *(const float4*)(w0 + i);
    float4 b1v = *(const float4*)(w1 + i);
#pragma unroll
    for (int k = 0; k < 4; ++k) {
      float4 a = *(const float4*)(xrow + k * XS_LD + i);
      acc[k][0] += a.x * b0.x + a.y * b0.y + a.z * b0.z + a.w * b0.w;
      acc[k][1] += a.x * b1v.x + a.y * b1v.y + a.z * b1v.z + a.w * b1v.w;
    }
  }

  int c0 = 2 * tx;
#pragma unroll
  for (int k = 0; k < 4; ++k) {
    int n = node0 + ty * 4 + k;
    if (n < N_NODES) {
      if (c0 < 16) {
        xw1b[n * HID + c0] = __float2bfloat16(acc[k][0]);
        xw1b[n * HID + c0 + 1] = __float2bfloat16(acc[k][1]);
      } else {
        xr1[n * HID + (c0 - 16)] = acc[k][0];
        xr1[n * HID + (c0 - 15)] = acc[k][1];
      }
    }
  }
}

// ---------------------------------------------------------------------------
// histB: bucket-count histogram with LDS pre-aggregation (782 counters)
// ---------------------------------------------------------------------------
__global__ __launch_bounds__(256) void histB_kernel(
    const int* __restrict__ dst, int* __restrict__ bcnt) {
  __shared__ int hc[NBUCK];
  for (int i = threadIdx.x; i < NBUCK; i += 256) hc[i] = 0;
  __syncthreads();
  int stride = gridDim.x * 256;
  for (int e = blockIdx.x * 256 + threadIdx.x; e < NEDGE; e += stride)
    atomicAdd(&hc[dst[e] >> 7], 1);
  __syncthreads();
  for (int i = threadIdx.x; i < NBUCK; i += 256) {
    int v = hc[i];
    if (v) atomicAdd(&bcnt[i], v);
  }
}

// ---------------------------------------------------------------------------
// scan: exclusive scan of 782 bucket counts (single block), init cursors
// ---------------------------------------------------------------------------
__global__ __launch_bounds__(1024) void scan_kernel(
    const int* __restrict__ bcnt, int* __restrict__ boff,
    int* __restrict__ bcursor) {
  __shared__ int s[1024];
  int v = (threadIdx.x < NBUCK) ? bcnt[threadIdx.x] : 0;
  s[threadIdx.x] = v;
  __syncthreads();
  for (int off = 1; off < 1024; off <<= 1) {
    int t = (threadIdx.x >= off) ? s[threadIdx.x - off] : 0;
    __syncthreads();
    s[threadIdx.x] += t;
    __syncthreads();
  }
  if (threadIdx.x < NBUCK) {
    int e = s[threadIdx.x] - v;
    boff[threadIdx.x] = e;
    bcursor[threadIdx.x] = e;
  }
  if (threadIdx.x == 0) boff[NBUCK] = NEDGE;
}

// ---------------------------------------------------------------------------
// binfill: append one 4B record per edge to its bucket.
// rec = src | (dst&127)<<17. Only 782 write frontiers -> dense line fills.
// ---------------------------------------------------------------------------
__global__ __launch_bounds__(256) void binfill_kernel(
    const int* __restrict__ src, const int* __restrict__ dst,
    int* __restrict__ bcursor, unsigned* __restrict__ recs) {
  int e = blockIdx.x * 256 + threadIdx.x;
  if (e >= NEDGE) return;
  int d = dst[e];
  int pos = atomicAdd(&bcursor[d >> 7], 1);
  recs[pos] = (unsigned)src[e] | ((unsigned)(d & 127) << 17);
}

// ---------------------------------------------------------------------------
// gatherL1: one block per bucket. LDS fp32 accumulation of 128x16 agg slice
// + LDS degree. Gather xw1b (bf16x16 = 32B/edge). Fused mean+xr1+b1+ELU,
// bf16 h out, fp32 deg out.
// ---------------------------------------------------------------------------
__global__ __launch_bounds__(256) void gatherL1_kernel(
    const int* __restrict__ boff, const unsigned* __restrict__ recs,
    const bf16* __restrict__ xw1b, const float* __restrict__ xr1,
    const float* __restrict__ b1, float* __restrict__ degf,
    bf16* __restrict__ hb) {
  __shared__ float agg[128 * HID];  // 8 KB
  __shared__ int ldeg[128];
  for (int i = threadIdx.x; i < 128 * HID; i += 256) agg[i] = 0.f;
  if (threadIdx.x < 128) ldeg[threadIdx.x] = 0;
  __syncthreads();

  int b = blockIdx.x;
  int beg = boff[b], end = boff[b + 1];
  int g = threadIdx.x >> 4;   // 16 edge-groups in flight
  int c = threadIdx.x & 15;   // channel
  for (int j = beg + g; j < end; j += 16) {
    unsigned r = recs[j];
    int s = r & 0x1FFFF;
    int dl = r >> 17;
    float v = __bfloat162float(xw1b[s * HID + c]);
    atomicAdd(&agg[dl * HID + c], v);
    if (c == 0) atomicAdd(&ldeg[dl], 1);
  }
  __syncthreads();

  int n0 = b * 128;
  for (int t = threadIdx.x; t < 128 * HID; t += 256) {
    int nl = t >> 4, cc = t & 15;
    int n = n0 + nl;
    if (n < N_NODES) {
      float d = fmaxf((float)ldeg[nl], 1.0f);
      float a = agg[t] / d + xr1[n * HID + cc] + b1[cc];
      a = (a > 0.f) ? a : expm1f(a);
      hb[n * HID + cc] = __float2bfloat16(a);
      if (cc == 0) degf[n] = (float)ldeg[nl];
    }
  }
}

// ---------------------------------------------------------------------------
// gatherL2: same structure; gathers hb, writes mean-normalized fp32 agg2n.
// ---------------------------------------------------------------------------
__global__ __launch_bounds__(256) void gatherL2_kernel(
    const int* __restrict__ boff, const unsigned* __restrict__ recs,
    const bf16* __restrict__ hb, const float* __restrict__ degf,
    float* __restrict__ agg2n) {
  __shared__ float agg[128 * HID];
  for (int i = threadIdx.x; i < 128 * HID; i += 256) agg[i] = 0.f;
  __syncthreads();

  int b = blockIdx.x;
  int beg = boff[b], end = boff[b + 1];
  int g = threadIdx.x >> 4;
  int c = threadIdx.x & 15;
  for (int j = beg + g; j < end; j += 16) {
    unsigned r = recs[j];
    int s = r & 0x1FFFF;
    int dl = r >> 17;
    float v = __bfloat162float(hb[s * HID + c]);
    atomicAdd(&agg[dl * HID + c], v);
  }
  __syncthreads();

  int n0 = b * 128;
  for (int t = threadIdx.x; t < 128 * HID; t += 256) {
    int nl = t >> 4, cc = t & 15;
    int n = n0 + nl;
    if (n < N_NODES)
      agg2n[n * HID + cc] = agg[t] / fmaxf(degf[n], 1.0f);
  }
}

// ---------------------------------------------------------------------------
// out: agg2n @ W2[1] + h @ root2 + b2, log_softmax, fp32 store.
// ---------------------------------------------------------------------------
__global__ __launch_bounds__(256) void out_kernel(
    const bf16* __restrict__ hb, const float* __restrict__ agg2n,
    const float* __restrict__ W2, const float* __restrict__ root2,
    const float* __restrict__ b2v, float* __restrict__ out) {
  __shared__ float Wl[HID * NCLS];
  __shared__ float Rl[HID * NCLS];
  __shared__ float Bl[NCLS];
  for (int i = threadIdx.x; i < HID * NCLS; i += blockDim.x) {
    Wl[i] = W2[HID * NCLS + i];
    Rl[i] = root2[i];
  }
  if (threadIdx.x < NCLS) Bl[threadIdx.x] = b2v[threadIdx.x];
  __syncthreads();

  int n = blockIdx.x * blockDim.x + threadIdx.x;
  if (n >= N_NODES) return;

  float hv[HID], av[HID];
#pragma unroll
  for (int c = 0; c < HID; ++c) {
    hv[c] = __bfloat162float(hb[n * HID + c]);
    av[c] = agg2n[n * HID + c];
  }
  float logit[NCLS];
#pragma unroll
  for (int j = 0; j < NCLS; ++j) logit[j] = Bl[j];
  for (int c = 0; c < HID; ++c) {
    float hc = hv[c], ac = av[c];
#pragma unroll
    for (int j = 0; j < NCLS; ++j)
      logit[j] += ac * Wl[c * NCLS + j] + hc * Rl[c * NCLS + j];
  }
  float m = -INFINITY;
#pragma unroll
  for (int j = 0; j < NCLS; ++j) m = fmaxf(m, logit[j]);
  float s = 0.f;
#pragma unroll
  for (int j = 0; j < NCLS; ++j) s += expf(logit[j] - m);
  float lse = m + logf(s);
#pragma unroll
  for (int j = 0; j < NCLS; ++j)
    out[(size_t)n * NCLS + j] = logit[j] - lse;
}

extern "C" void kernel_launch(void* const* d_in, const int* in_sizes, int n_in,
                              void* d_out, int out_size, void* d_ws,
                              size_t ws_size, hipStream_t stream) {
  const float* x = (const float*)d_in[0];
  const int* ei = (const int*)d_in[1];  // (2, E): src row then dst row
  const float* W1 = (const float*)d_in[2];
  const float* root1 = (const float*)d_in[3];
  const float* b1 = (const float*)d_in[4];
  const float* W2 = (const float*)d_in[5];
  const float* root2 = (const float*)d_in[6];
  const float* b2v = (const float*)d_in[7];
  float* out = (float*)d_out;

  const int* src = ei;
  const int* dstp = ei + NEDGE;

  // workspace layout (bytes), ~32.4 MB:
  char* w = (char*)d_ws;
  int* boff = (int*)w;                 w += 4096;          // NBUCK+1 ints
  int* bcnt = (int*)w;                 w += 4096;
  int* bcursor = (int*)w;              w += 4096;
  float* degf = (float*)w;             w += (size_t)N_NODES * 4;
  unsigned* recs = (unsigned*)w;       w += (size_t)NEDGE * 4;
  bf16* xw1b = (bf16*)w;               w += (size_t)N_NODES * HID * 2;
  bf16* hb = (bf16*)w;                 w += (size_t)N_NODES * HID * 2;
  float* xr1 = (float*)w;              w += (size_t)N_NODES * HID * 4;
  float* agg2n = (float*)w;            w += (size_t)N_NODES * HID * 4;

  hipMemsetAsync(bcnt, 0, 4096, stream);

  proj1_kernel<<<(N_NODES + 63) / 64, 256, 0, stream>>>(x, W1, root1, xw1b,
                                                        xr1);
  histB_kernel<<<256, 256, 0, stream>>>(dstp, bcnt);
  scan_kernel<<<1, 1024, 0, stream>>>(bcnt, boff, bcursor);
  binfill_kernel<<<(NEDGE + 255) / 256, 256, 0, stream>>>(src, dstp, bcursor,
                                                          recs);
  gatherL1_kernel<<<NBUCK, 256, 0, stream>>>(boff, recs, xw1b, xr1, b1, degf,
                                             hb);
  gatherL2_kernel<<<NBUCK, 256, 0, stream>>>(boff, recs, hb, degf, agg2n);
  out_kernel<<<(N_NODES + 255) / 256, 256, 0, stream>>>(hb, agg2n, W2, root2,
                                                        b2v, out);
}

// Round 5
// 635.018 us; speedup vs baseline: 2.5318x; 2.5318x over previous
//
#include <hip/hip_runtime.h>
#include <hip/hip_bf16.h>
#include <hip/hip_fp16.h>

#define N_NODES 100000
#define FIN 128
#define HID 16
#define NCLS 40
#define NEDGE 3200000
#define XS_LD 132   // padded row stride (floats) for x tile
#define W_LD 132    // padded row stride for transposed weight panel

// ---------------------------------------------------------------------------
// proj1: xw1h = fp16(x @ W1[1]), xr1 = x @ root1 (fp32).
// Block: 256 threads, 64 nodes. Thread micro-tile: 4 nodes x 2 cols.
// All inner-loop LDS reads are ds_read_b128 (float4).
// ---------------------------------------------------------------------------
__global__ __launch_bounds__(256) void proj1_kernel(
    const float* __restrict__ x, const float* __restrict__ W1,
    const float* __restrict__ root1,
    __half* __restrict__ xw1h, float* __restrict__ xr1) {
  __shared__ float xs[64 * XS_LD];   // 33 KB
  __shared__ float WLt[32 * W_LD];   // 16.5 KB, [col][i] transposed

  int tid = threadIdx.x;
  int node0 = blockIdx.x * 64;

  for (int t = tid; t < 32 * FIN; t += 256) {
    int c = t >> 7, i = t & 127;
    WLt[c * W_LD + i] =
        (c < 16) ? W1[FIN * HID + i * HID + c] : root1[i * HID + (c - 16)];
  }
#pragma unroll
  for (int k = 0; k < 8; ++k) {
    int f = k * 256 + tid;
    int r = f >> 5;
    int cw = f & 31;
    float4 v = make_float4(0.f, 0.f, 0.f, 0.f);
    if (node0 + r < N_NODES)
      v = *(const float4*)(x + (size_t)(node0 + r) * FIN + cw * 4);
    *(float4*)(xs + r * XS_LD + cw * 4) = v;
  }
  __syncthreads();

  int tx = tid & 15;
  int ty = tid >> 4;
  const float* w0 = WLt + (2 * tx) * W_LD;
  const float* w1 = w0 + W_LD;
  const float* xrow = xs + (ty * 4) * XS_LD;

  float acc[4][2] = {{0.f, 0.f}, {0.f, 0.f}, {0.f, 0.f}, {0.f, 0.f}};
#pragma unroll 8
  for (int i = 0; i < FIN; i += 4) {
    float4 b0 = *(const float4*)(w0 + i);
    float4 b1v = *(const float4*)(w1 + i);
#pragma unroll
    for (int k = 0; k < 4; ++k) {
      float4 a = *(const float4*)(xrow + k * XS_LD + i);
      acc[k][0] += a.x * b0.x + a.y * b0.y + a.z * b0.z + a.w * b0.w;
      acc[k][1] += a.x * b1v.x + a.y * b1v.y + a.z * b1v.z + a.w * b1v.w;
    }
  }

  int c0 = 2 * tx;
#pragma unroll
  for (int k = 0; k < 4; ++k) {
    int n = node0 + ty * 4 + k;
    if (n < N_NODES) {
      if (c0 < 16) {
        xw1h[n * HID + c0] = __float2half(acc[k][0]);
        xw1h[n * HID + c0 + 1] = __float2half(acc[k][1]);
      } else {
        xr1[n * HID + (c0 - 16)] = acc[k][0];
        xr1[n * HID + (c0 - 15)] = acc[k][1];
      }
    }
  }
}

// ---------------------------------------------------------------------------
// scatter_pk: per-edge scatter-add of 16 fp16 channels as 8 packed-fp16
// atomics (global_atomic_pk_add_f16). thread t -> edge e = t/8, pair c2 = t%8.
// DO_DEG: lane c2==0 also counts degree (fp32 atomic).
// ---------------------------------------------------------------------------
template <bool DO_DEG>
__global__ __launch_bounds__(256) void scatter_pk_kernel(
    const int* __restrict__ src, const int* __restrict__ dst,
    const __half2* __restrict__ val, __half2* __restrict__ agg,
    float* __restrict__ degf) {
  int t = blockIdx.x * 256 + threadIdx.x;   // grid sized exactly NEDGE*8
  int e = t >> 3;
  int c2 = t & 7;
  int s = src[e];
  int d = dst[e];
  __half2 v = val[s * 8 + c2];
  unsafeAtomicAdd(&agg[d * 8 + c2], v);
  if (DO_DEG && c2 == 0) atomicAdd(&degf[d], 1.0f);
}

// ---------------------------------------------------------------------------
// hidden: h = fp16(elu(agg1/deg + xr1 + b1)); processes half2 pairs.
// ---------------------------------------------------------------------------
__global__ __launch_bounds__(256) void hidden_kernel(
    const __half2* __restrict__ agg1, const float* __restrict__ xr1,
    const float* __restrict__ b1, const float* __restrict__ degf,
    __half2* __restrict__ hb) {
  int t = blockIdx.x * 256 + threadIdx.x;   // grid sized exactly N*8
  int n = t >> 3;
  int c2 = t & 7;
  float inv = 1.0f / fmaxf(degf[n], 1.0f);
  float2 a = __half22float2(agg1[t]);
  float2 r = ((const float2*)xr1)[t];
  float2 bb = ((const float2*)b1)[c2];
  float a0 = a.x * inv + r.x + bb.x;
  float a1 = a.y * inv + r.y + bb.y;
  a0 = (a0 > 0.f) ? a0 : expm1f(a0);
  a1 = (a1 > 0.f) ? a1 : expm1f(a1);
  hb[t] = __floats2half2_rn(a0, a1);
}

// ---------------------------------------------------------------------------
// out: (agg2/deg) @ W2[1] + h @ root2 + b2, log_softmax, fp32 store.
// ---------------------------------------------------------------------------
__global__ __launch_bounds__(256) void out_kernel(
    const __half2* __restrict__ hb, const __half2* __restrict__ agg2,
    const float* __restrict__ degf, const float* __restrict__ W2,
    const float* __restrict__ root2, const float* __restrict__ b2v,
    float* __restrict__ out) {
  __shared__ float Wl[HID * NCLS];
  __shared__ float Rl[HID * NCLS];
  __shared__ float Bl[NCLS];
  for (int i = threadIdx.x; i < HID * NCLS; i += blockDim.x) {
    Wl[i] = W2[HID * NCLS + i];
    Rl[i] = root2[i];
  }
  if (threadIdx.x < NCLS) Bl[threadIdx.x] = b2v[threadIdx.x];
  __syncthreads();

  int n = blockIdx.x * blockDim.x + threadIdx.x;
  if (n >= N_NODES) return;

  float inv = 1.0f / fmaxf(degf[n], 1.0f);
  float hv[HID], av[HID];
#pragma unroll
  for (int c2 = 0; c2 < 8; ++c2) {
    float2 hh = __half22float2(hb[n * 8 + c2]);
    float2 aa = __half22float2(agg2[n * 8 + c2]);
    hv[2 * c2] = hh.x;
    hv[2 * c2 + 1] = hh.y;
    av[2 * c2] = aa.x * inv;
    av[2 * c2 + 1] = aa.y * inv;
  }
  float logit[NCLS];
#pragma unroll
  for (int j = 0; j < NCLS; ++j) logit[j] = Bl[j];
  for (int c = 0; c < HID; ++c) {
    float hc = hv[c], ac = av[c];
#pragma unroll
    for (int j = 0; j < NCLS; ++j)
      logit[j] += ac * Wl[c * NCLS + j] + hc * Rl[c * NCLS + j];
  }
  float m = -INFINITY;
#pragma unroll
  for (int j = 0; j < NCLS; ++j) m = fmaxf(m, logit[j]);
  float s = 0.f;
#pragma unroll
  for (int j = 0; j < NCLS; ++j) s += expf(logit[j] - m);
  float lse = m + logf(s);
#pragma unroll
  for (int j = 0; j < NCLS; ++j)
    out[(size_t)n * NCLS + j] = logit[j] - lse;
}

extern "C" void kernel_launch(void* const* d_in, const int* in_sizes, int n_in,
                              void* d_out, int out_size, void* d_ws,
                              size_t ws_size, hipStream_t stream) {
  const float* x = (const float*)d_in[0];
  const int* ei = (const int*)d_in[1];  // (2, E): src row then dst row
  const float* W1 = (const float*)d_in[2];
  const float* root1 = (const float*)d_in[3];
  const float* b1 = (const float*)d_in[4];
  const float* W2 = (const float*)d_in[5];
  const float* root2 = (const float*)d_in[6];
  const float* b2v = (const float*)d_in[7];
  float* out = (float*)d_out;

  const int* src = ei;
  const int* dstp = ei + NEDGE;

  // workspace layout (bytes), ~20 MB:
  // [degf N f32][agg1 16N f16][agg2 16N f16]  <- zeroed together (6.8 MB)
  // [xw1h 16N f16][hb 16N f16][xr1 16N f32]
  char* w = (char*)d_ws;
  float* degf = (float*)w;        w += (size_t)N_NODES * 4;
  __half2* agg1 = (__half2*)w;    w += (size_t)N_NODES * HID * 2;
  __half2* agg2 = (__half2*)w;    w += (size_t)N_NODES * HID * 2;
  __half* xw1h = (__half*)w;      w += (size_t)N_NODES * HID * 2;
  __half2* hb = (__half2*)w;      w += (size_t)N_NODES * HID * 2;
  float* xr1 = (float*)w;         w += (size_t)N_NODES * HID * 4;

  // zero degf + agg1 + agg2 in one shot (fp16 +0.0 == all-zero bits)
  hipMemsetAsync(degf, 0, (size_t)N_NODES * (4 + 2 * HID * 2), stream);

  proj1_kernel<<<(N_NODES + 63) / 64, 256, 0, stream>>>(x, W1, root1, xw1h,
                                                        xr1);
  scatter_pk_kernel<true><<<NEDGE * 8 / 256, 256, 0, stream>>>(
      src, dstp, (const __half2*)xw1h, agg1, degf);
  hidden_kernel<<<N_NODES * 8 / 256, 256, 0, stream>>>(agg1, xr1, b1, degf,
                                                       hb);
  scatter_pk_kernel<false><<<NEDGE * 8 / 256, 256, 0, stream>>>(
      src, dstp, (const __half2*)hb, agg2, nullptr);
  out_kernel<<<(N_NODES + 255) / 256, 256, 0, stream>>>(hb, agg2, degf, W2,
                                                        root2, b2v, out);
}